// Round 16
// baseline (94.277 us; speedup 1.0000x reference)
//
#include <hip/hip_runtime.h>

// Problem constants (from reference setup_inputs).
constexpr int B = 8;
constexpr int N = 16384;
constexpr int M = 1024;
constexpr int C = 256;
constexpr int PTS   = 64;   // points per tile
constexpr int TILES = 4;    // tiles per block

typedef float vf16 __attribute__((ext_vector_type(16)));

// Producer-consumer wave specialization. Block = 512 threads = 8 waves:
//   waves 0-3 (scanners): r10's proven scan — SMEM candidate stream
//     (s_load_dwordx16 x3 per 16-cand chunk) + bit-exact select ladder,
//     wave q covers candidate quarter q. Writes 3 u64 keys/point to LDS.
//   waves 4-7 (writers): per point, merge the 12 keys (broadcast LDS reads,
//     exact u64 ladder = top_k lowest-index tie-break), compute IDW weights,
//     gather 3 feature rows, store. Memory phase runs CONCURRENTLY with the
//     scanners' VALU phase on the same CU (separate pipes overlap).
// Sync: LDS epoch counters (scan_cnt/write_cnt per buffer) with acquire/
// release atomics + s_sleep spin. Block-internal only -> deadlock-free,
// deterministic, graph-capture-safe. Keys double-buffered (2 x 6KB).
// Distance is bit-exact vs the reference: (dx*dx+dy*dy)+dz*dz separately
// rounded; (c-x) squares identically to (x-c). Strict-< ladder everywhere.
// XCD swizzle: batch = blk & 7 pins each batch's 1MB feats to one XCD's L2.
__global__ __launch_bounds__(512, 4) void upsample_idw_kernel(
    const float* __restrict__ xyz,          // [B,N,3]
    const float* __restrict__ sxyz,         // [B,M,3]
    const float* __restrict__ feats,        // [B,M,C]
    const int*   __restrict__ masks,        // [B,N]
    float*       __restrict__ out)          // [B,N,C]
{
    const int tid = threadIdx.x;
    const int w   = tid >> 6;               // wave id 0..7
    const int l   = tid & 63;               // lane
    const int blk = blockIdx.x;
    const int b     = blk & 7;              // batch == XCD (round-robin dispatch)
    const int pbase = (blk >> 3) * (TILES * PTS);   // first point of this block

    __shared__ unsigned long long s_key[2][PTS][4][3];   // 12KB double buffer
    __shared__ int s_scan_cnt[2];
    __shared__ int s_write_cnt[2];

    if (tid < 2) { s_scan_cnt[tid] = 0; s_write_cnt[tid] = 0; }
    __syncthreads();                        // the only full barrier

    const float* bbase = sxyz + (size_t)b * (M * 3);

    if (w < 4) {
        // ================= SCANNER role (waves 0-3) =================
        const int q = w;                    // candidate quarter
        const int qoff = __builtin_amdgcn_readfirstlane(q * (256 * 12));

        for (int t = 0; t < TILES; ++t) {
            const int buf = t & 1, k = t >> 1;
            if (k > 0) {                    // wait for writers to free buffer
                while (__hip_atomic_load(&s_write_cnt[buf], __ATOMIC_ACQUIRE,
                                         __HIP_MEMORY_SCOPE_WORKGROUP) < 4 * k)
                    __builtin_amdgcn_s_sleep(1);
            }

            const int pt = pbase + t * PTS + l;
            const float* xp = xyz + ((size_t)b * N + pt) * 3;
            const float x = xp[0], y = xp[1], z = xp[2];

            float d0 = __builtin_inff(), d1 = __builtin_inff(), d2 = __builtin_inff();
            int   i0 = 0, i1 = 0, i2 = 0;

            for (int ch = 0; ch < 16; ++ch) {   // 16 chunks x 16 candidates
                vf16 ca, cb, cc;
                const int off = qoff + ch * 192;
                asm volatile(
                    "s_load_dwordx16 %0, %3, %4\n\t"
                    "s_load_dwordx16 %1, %3, %4 offset:64\n\t"
                    "s_load_dwordx16 %2, %3, %4 offset:128\n\t"
                    "s_waitcnt lgkmcnt(0)"
                    : "=&s"(ca), "=&s"(cb), "=&s"(cc)
                    : "s"(bbase), "s"(off));
                #pragma unroll
                for (int j = 0; j < 16; ++j) {
                    const int f0 = 3 * j, f1 = 3 * j + 1, f2 = 3 * j + 2;
                    const float cx = (f0 < 16) ? ca[f0 & 15] : (f0 < 32) ? cb[f0 & 15] : cc[f0 & 15];
                    const float cy = (f1 < 16) ? ca[f1 & 15] : (f1 < 32) ? cb[f1 & 15] : cc[f1 & 15];
                    const float cz = (f2 < 16) ? ca[f2 & 15] : (f2 < 32) ? cb[f2 & 15] : cc[f2 & 15];
                    const float dx = __fsub_rn(cx, x);
                    const float dy = __fsub_rn(cy, y);
                    const float dz = __fsub_rn(cz, z);
                    const float d  = __fadd_rn(__fadd_rn(__fmul_rn(dx, dx), __fmul_rn(dy, dy)),
                                               __fmul_rn(dz, dz));
                    const int m = ch * 16 + j;
                    const bool lt0 = d < d0, lt1 = d < d1, lt2 = d < d2;
                    i2 = lt1 ? i1 : (lt2 ? m : i2);
                    i1 = lt0 ? i0 : (lt1 ? m : i1);
                    i0 = lt0 ? m  : i0;
                    const float nd2 = __builtin_amdgcn_fmed3f(d1, d2, d);
                    const float nd1 = __builtin_amdgcn_fmed3f(d0, d1, d);
                    d2 = nd2; d1 = nd1; d0 = fminf(d0, d);
                }
            }

            const unsigned base = (unsigned)(q * 256);
            s_key[buf][l][q][0] = ((unsigned long long)__float_as_uint(d0) << 32) | (base + (unsigned)i0);
            s_key[buf][l][q][1] = ((unsigned long long)__float_as_uint(d1) << 32) | (base + (unsigned)i1);
            s_key[buf][l][q][2] = ((unsigned long long)__float_as_uint(d2) << 32) | (base + (unsigned)i2);

            if (l == 0)                      // publish (release orders LDS writes)
                __hip_atomic_fetch_add(&s_scan_cnt[buf], 1, __ATOMIC_RELEASE,
                                       __HIP_MEMORY_SCOPE_WORKGROUP);
        }
    } else {
        // ================= WRITER role (waves 4-7) =================
        const int wv = w - 4;               // 0..3
        const float4* Fb4 = (const float4*)(feats + (size_t)b * (M * C));

        for (int t = 0; t < TILES; ++t) {
            const int buf = t & 1, k = t >> 1;
            while (__hip_atomic_load(&s_scan_cnt[buf], __ATOMIC_ACQUIRE,
                                     __HIP_MEMORY_SCOPE_WORKGROUP) < 4 * (k + 1))
                __builtin_amdgcn_s_sleep(1);

            float4* op4 = (float4*)(out + ((size_t)b * N + pbase + t * PTS) * C);

            for (int i = 0; i < 16; ++i) {
                const int p = 4 * i + wv;    // wave-uniform point
                // Merge 12 keys (uniform-address LDS broadcast reads).
                unsigned long long k0 = ~0ULL, k1 = ~0ULL, k2 = ~0ULL;
                #pragma unroll
                for (int q = 0; q < 4; ++q) {
                    #pragma unroll
                    for (int s = 0; s < 3; ++s) {
                        const unsigned long long kk = s_key[buf][p][q][s];
                        const bool lt0 = kk < k0, lt1 = kk < k1, lt2 = kk < k2;
                        k2 = lt1 ? k1 : (lt2 ? kk : k2);
                        k1 = lt0 ? k0 : (lt1 ? kk : k1);
                        k0 = lt0 ? kk : k0;
                    }
                }
                const float e0 = __uint_as_float((unsigned)(k0 >> 32));
                const float e1 = __uint_as_float((unsigned)(k1 >> 32));
                const float e2 = __uint_as_float((unsigned)(k2 >> 32));
                const float m0 = fmaxf(e0, 1e-10f);
                const float m1 = fmaxf(e1, 1e-10f);
                const float m2 = fmaxf(e2, 1e-10f);
                float w0 = 1.0f / (m0 * m0 + 1e-10f);
                float w1 = 1.0f / (m1 * m1 + 1e-10f);
                float w2 = 1.0f / (m2 * m2 + 1e-10f);
                const int valid = masks[(size_t)b * N + pbase + t * PTS + p]; // uniform
                const float scale = valid ? (1.0f / (w0 + w1 + w2)) : 0.0f;
                w0 *= scale; w1 *= scale; w2 *= scale;

                float4 acc = make_float4(0.f, 0.f, 0.f, 0.f);
                if (valid) {                 // uniform branch
                    const int j0 = (int)(unsigned)k0;
                    const int j1 = (int)(unsigned)k1;
                    const int j2 = (int)(unsigned)k2;
                    const float4 f0 = Fb4[j0 * 64 + l];
                    const float4 f1 = Fb4[j1 * 64 + l];
                    const float4 f2 = Fb4[j2 * 64 + l];
                    acc.x = fmaf(w2, f2.x, fmaf(w1, f1.x, w0 * f0.x));
                    acc.y = fmaf(w2, f2.y, fmaf(w1, f1.y, w0 * f0.y));
                    acc.z = fmaf(w2, f2.z, fmaf(w1, f1.z, w0 * f0.z));
                    acc.w = fmaf(w2, f2.w, fmaf(w1, f1.w, w0 * f0.w));
                }
                op4[p * 64 + l] = acc;
            }

            if (l == 0)                      // mark buffer consumed
                __hip_atomic_fetch_add(&s_write_cnt[buf], 1, __ATOMIC_RELEASE,
                                       __HIP_MEMORY_SCOPE_WORKGROUP);
        }
    }
}

extern "C" void kernel_launch(void* const* d_in, const int* in_sizes, int n_in,
                              void* d_out, int out_size, void* d_ws, size_t ws_size,
                              hipStream_t stream) {
    const float* xyz   = (const float*)d_in[0];
    const float* sxyz  = (const float*)d_in[1];
    const float* feats = (const float*)d_in[2];
    const int*   masks = (const int*)d_in[3];
    float*       out   = (float*)d_out;

    dim3 grid(B * N / (TILES * PTS));   // 512 blocks
    dim3 block(512);
    hipLaunchKernelGGL(upsample_idw_kernel, grid, block, 0, stream,
                       xyz, sxyz, feats, masks, out);
}